// Round 3
// baseline (578.839 us; speedup 1.0000x reference)
//
#include <hip/hip_runtime.h>

// TCM_77464030151162: x(N,128)@w1+b1 -> split 64/64 -> two gathered 3^3 sparse
// convs (27 offsets, 64x64 each, ReLU) -> +2*conv_x residual -> concat@w2+b2 -> +x.
// Wire dtypes fp32; tolerance is bf16-grade -> bf16 MFMA, fp32 accumulate.
// R2: latency-bound convs (MfmaUtil 6.4%, occ 27.7%) -> 16 rows/wave (2x waves)
//     + ring-buffer prefetch (idx dist 4, gather dist 2); k_cvt fused into gemm_in.

#define N_PTS 100000
#define NBLK64 1563 // ceil(100000/64)

typedef __attribute__((ext_vector_type(8))) short frag_ab; // 8 bf16 (4 VGPRs)
typedef __attribute__((ext_vector_type(4))) float f32x4;   // MFMA 16x16 C/D

#define ZFRAG frag_ab{0, 0, 0, 0, 0, 0, 0, 0}

__device__ __forceinline__ unsigned short f2bf(float f) {
  union { float f; unsigned int i; } v; v.f = f;
  unsigned int r = v.i + 0x7fffu + ((v.i >> 16) & 1u); // RNE
  return (unsigned short)(r >> 16);
}
__device__ __forceinline__ float bf2f(unsigned short u) {
  union { unsigned int i; float f; } v; v.i = ((unsigned int)u) << 16; return v.f;
}

// ---- weight convert+transpose: Wt[d][c] = bf16(W[c][d]) ----
__global__ __launch_bounds__(256) void k_prep(
    const float* __restrict__ w1, const float* __restrict__ w2,
    const float* __restrict__ rw1, const float* __restrict__ rw2,
    unsigned short* __restrict__ w1T, unsigned short* __restrict__ w2T,
    unsigned short* __restrict__ rw1T, unsigned short* __restrict__ rw2T) {
  int t = blockIdx.x * 256 + threadIdx.x;
  if (t < 128 * 128) {
    int c = t >> 7, d = t & 127;
    w1T[d * 128 + c] = f2bf(w1[t]);
    w2T[d * 128 + c] = f2bf(w2[t]);
  }
  if (t < 27 * 64 * 64) {
    int k = t >> 12, r = t & 4095, c = r >> 6, d = r & 63;
    int o = (k << 12) + d * 64 + c;
    rw1T[o] = f2bf(rw1[t]);
    rw2T[o] = f2bf(rw2[t]);
  }
}

// ---- y = bf16(x) @ w1 + b1  (M=100000, N=128, K=128); fp32 x read, bf16 y ----
// wave = 16 rows x 128 cols; block = 64 rows.
__global__ __launch_bounds__(256) void k_gemm_in(
    const float* __restrict__ x, const unsigned short* __restrict__ w1T,
    const float* __restrict__ b1, unsigned short* __restrict__ y) {
  const int lane = threadIdx.x & 63;
  const int w = threadIdx.x >> 6;
  const int m16 = lane & 15, q = lane >> 4;
  const int rowbase = blockIdx.x * 64 + w * 16;
  const int r0 = rowbase + m16;
  const int rc = r0 < N_PTS ? r0 : N_PTS - 1;
  f32x4 acc[8] = {};
#pragma unroll
  for (int kk = 0; kk < 4; ++kk) {
    const float* xp = x + (size_t)rc * 128 + kk * 32 + q * 8;
    float4 f0 = *(const float4*)xp;
    float4 f1 = *(const float4*)(xp + 4);
    frag_ab a;
    a[0] = (short)f2bf(f0.x); a[1] = (short)f2bf(f0.y);
    a[2] = (short)f2bf(f0.z); a[3] = (short)f2bf(f0.w);
    a[4] = (short)f2bf(f1.x); a[5] = (short)f2bf(f1.y);
    a[6] = (short)f2bf(f1.z); a[7] = (short)f2bf(f1.w);
#pragma unroll
    for (int ct = 0; ct < 8; ++ct) {
      frag_ab b = *(const frag_ab*)(w1T + (size_t)(ct * 16 + m16) * 128 + kk * 32 + q * 8);
      acc[ct] = __builtin_amdgcn_mfma_f32_16x16x32_bf16(a, b, acc[ct], 0, 0, 0);
    }
  }
#pragma unroll
  for (int ct = 0; ct < 8; ++ct) {
    int col = ct * 16 + m16;
    float bias = b1[col];
#pragma unroll
    for (int j = 0; j < 4; ++j) {
      int r = rowbase + q * 4 + j;
      if (r < N_PTS) y[(size_t)r * 128 + col] = f2bf(acc[ct][j] + bias);
    }
  }
}

// ---- gathered sparse conv: out[n,:] = relu(sum_k feat[nbr[k,n],:] @ rw[k] + rb)
// FUSE: out += 2*res[n,:64] (res bf16, row stride 128). out bf16 (N x 64).
// wave = 16 rows; idx prefetch distance 4 (ring 4), gather distance 2 (ring 2).
template <bool FUSE>
__global__ __launch_bounds__(256) void k_conv(
    const unsigned short* __restrict__ feat, const int fstride,
    const int* __restrict__ nbr,
    const unsigned short* __restrict__ rwT, const float* __restrict__ rb,
    const unsigned short* __restrict__ res, unsigned short* __restrict__ out) {
  const int lane = threadIdx.x & 63;
  const int w = threadIdx.x >> 6;
  const int m16 = lane & 15, q = lane >> 4;
  const int rowbase = blockIdx.x * 64 + w * 16;
  const int p = rowbase + m16;
  f32x4 acc[4] = {};

  int idxr[4];
#pragma unroll
  for (int j = 0; j < 4; ++j)
    idxr[j] = (p < N_PTS) ? nbr[j * N_PTS + p] : -1;

  frag_ab A0[2], A1[2];
#pragma unroll
  for (int j = 0; j < 2; ++j) {
    A0[j] = ZFRAG; A1[j] = ZFRAG;
    if (idxr[j] >= 0) {
      const unsigned short* fp = feat + (size_t)idxr[j] * fstride + q * 8;
      A0[j] = *(const frag_ab*)fp;
      A1[j] = *(const frag_ab*)(fp + 32);
    }
  }

#pragma unroll
  for (int k = 0; k < 27; ++k) {
    if (k + 4 < 27)
      idxr[k & 3] = (p < N_PTS) ? nbr[(k + 4) * N_PTS + p] : -1;
    frag_ab n0 = ZFRAG, n1 = ZFRAG;
    if (k + 2 < 27) {
      int ix = idxr[(k + 2) & 3];
      if (ix >= 0) {
        const unsigned short* fp = feat + (size_t)ix * fstride + q * 8;
        n0 = *(const frag_ab*)fp;
        n1 = *(const frag_ab*)(fp + 32);
      }
    }
    const unsigned short* wk = rwT + (k << 12);
    frag_ab a0 = A0[k & 1], a1 = A1[k & 1];
#pragma unroll
    for (int ct = 0; ct < 4; ++ct) {
      frag_ab b0 = *(const frag_ab*)(wk + (ct * 16 + m16) * 64 + q * 8);
      frag_ab b1 = *(const frag_ab*)(wk + (ct * 16 + m16) * 64 + 32 + q * 8);
      acc[ct] = __builtin_amdgcn_mfma_f32_16x16x32_bf16(a0, b0, acc[ct], 0, 0, 0);
      acc[ct] = __builtin_amdgcn_mfma_f32_16x16x32_bf16(a1, b1, acc[ct], 0, 0, 0);
    }
    A0[k & 1] = n0; A1[k & 1] = n1;
  }

#pragma unroll
  for (int ct = 0; ct < 4; ++ct) {
    int col = ct * 16 + m16;
    float bias = rb[col];
#pragma unroll
    for (int j = 0; j < 4; ++j) {
      int r = rowbase + q * 4 + j;
      if (r < N_PTS) {
        float v = acc[ct][j] + bias;
        v = v > 0.f ? v : 0.f;
        if constexpr (FUSE) v += 2.f * bf2f(res[(size_t)r * 128 + col]);
        out[(size_t)r * 64 + col] = f2bf(v);
      }
    }
  }
}

// ---- out = x + [z1 | y[:,64:]] @ w2 + b2 ; x/out fp32 ----
__global__ __launch_bounds__(256) void k_gemm_out(
    const float* __restrict__ x, const unsigned short* __restrict__ z1,
    const unsigned short* __restrict__ y, const unsigned short* __restrict__ w2T,
    const float* __restrict__ b2, float* __restrict__ out) {
  const int lane = threadIdx.x & 63;
  const int w = threadIdx.x >> 6;
  const int m16 = lane & 15, q = lane >> 4;
  const int rowbase = blockIdx.x * 64 + w * 16;
  const int r0 = rowbase + m16;
  const int rc = r0 < N_PTS ? r0 : N_PTS - 1;
  f32x4 acc[8] = {};
#pragma unroll
  for (int kk = 0; kk < 4; ++kk) {
    const unsigned short* ap = (kk < 2)
        ? (z1 + (size_t)rc * 64 + kk * 32 + q * 8)
        : (y + (size_t)rc * 128 + 64 + (kk - 2) * 32 + q * 8);
    frag_ab a = *(const frag_ab*)ap;
#pragma unroll
    for (int ct = 0; ct < 8; ++ct) {
      frag_ab b = *(const frag_ab*)(w2T + (size_t)(ct * 16 + m16) * 128 + kk * 32 + q * 8);
      acc[ct] = __builtin_amdgcn_mfma_f32_16x16x32_bf16(a, b, acc[ct], 0, 0, 0);
    }
  }
#pragma unroll
  for (int ct = 0; ct < 8; ++ct) {
    int col = ct * 16 + m16;
    float bias = b2[col];
#pragma unroll
    for (int j = 0; j < 4; ++j) {
      int r = rowbase + q * 4 + j;
      if (r < N_PTS) {
        size_t o = (size_t)r * 128 + col;
        out[o] = acc[ct][j] + bias + x[o];
      }
    }
  }
}

extern "C" void kernel_launch(void* const* d_in, const int* in_sizes, int n_in,
                              void* d_out, int out_size, void* d_ws, size_t ws_size,
                              hipStream_t stream) {
  const float* x   = (const float*)d_in[0];
  const float* w1  = (const float*)d_in[1];
  const float* b1  = (const float*)d_in[2];
  const float* w2  = (const float*)d_in[3];
  const float* b2  = (const float*)d_in[4];
  const float* rw1 = (const float*)d_in[5];
  const float* rb1 = (const float*)d_in[6];
  const float* rw2 = (const float*)d_in[7];
  const float* rb2 = (const float*)d_in[8];
  const int* nbr = (const int*)d_in[9];
  float* out = (float*)d_out;

  char* ws = (char*)d_ws;
  unsigned short* w1T  = (unsigned short*)(ws);                       // 32 KB
  unsigned short* w2T  = (unsigned short*)(ws + 32768);               // 32 KB
  unsigned short* rw1T = (unsigned short*)(ws + 65536);               // 216 KB
  unsigned short* rw2T = (unsigned short*)(ws + 286720);              // 216 KB
  unsigned short* y    = (unsigned short*)(ws + 507904);              // 25.6 MB
  unsigned short* r1   = (unsigned short*)(ws + 507904 + 25600000);   // 12.8 MB
  unsigned short* z1   = (unsigned short*)(ws + 507904 + 38400000);   // 12.8 MB

  k_prep<<<432, 256, 0, stream>>>(w1, w2, rw1, rw2, w1T, w2T, rw1T, rw2T);
  k_gemm_in<<<NBLK64, 256, 0, stream>>>(x, w1T, b1, y);
  k_conv<false><<<NBLK64, 256, 0, stream>>>(y, 128, nbr, rw1T, rb1, nullptr, r1);
  k_conv<true><<<NBLK64, 256, 0, stream>>>(r1, 64, nbr, rw2T, rb2, y, z1);
  k_gemm_out<<<NBLK64, 256, 0, stream>>>(x, z1, y, w2T, b2, out);
}

// Round 4
// 242.396 us; speedup vs baseline: 2.3880x; 2.3880x over previous
//
#include <hip/hip_runtime.h>

// TCM_77464030151162: x(N,128)@w1+b1 -> split 64/64 -> two gathered 3^3 sparse
// convs (27 offsets, 64x64 each, ReLU) -> +2*conv_x residual -> concat@w2+b2 -> +x.
// fp32 wire, bf16 MFMA compute.
// R4: B-fragments moved to LDS (double-buffered global_load_lds staging, XOR-swizzled
// layout baked into k_prep to kill the 128B-stride bank conflict). Conv: 32 rows/wave,
// idx prefetch dist 2, A-gather + stage dist 1. GEMMs: 32KB weights staged once.

#define N_PTS 100000
#define NBLK128 782 // ceil(100000/128)

typedef __attribute__((ext_vector_type(8))) short frag_ab; // 8 bf16 (4 VGPRs)
typedef __attribute__((ext_vector_type(4))) float f32x4;   // MFMA 16x16 C/D
#define ZFRAG frag_ab{0, 0, 0, 0, 0, 0, 0, 0}

__device__ __forceinline__ unsigned short f2bf(float f) {
  union { float f; unsigned int i; } v; v.f = f;
  unsigned int r = v.i + 0x7fffu + ((v.i >> 16) & 1u); // RNE
  return (unsigned short)(r >> 16);
}
__device__ __forceinline__ float bf2f(unsigned short u) {
  union { unsigned int i; float f; } v; v.i = ((unsigned int)u) << 16; return v.f;
}

// async global->LDS, 16B per lane. LDS dest = wave-uniform base + lane*16 (m104).
__device__ __forceinline__ void gload_lds16(const unsigned short* g, unsigned short* l) {
  __builtin_amdgcn_global_load_lds(
      (const __attribute__((address_space(1))) unsigned int*)g,
      (__attribute__((address_space(3))) unsigned int*)(unsigned int)(size_t)l,
      16, 0, 0);
}

// ---- weight convert+transpose+swizzle ----
// w1T/w2T: logical (d,c) d=0..127 out-col, c=0..127 k. 16B chunk (c>>3) stored at
// chunk^(d&15). rw1T/rw2T: (k,d,c) 64x64; chunk (c>>3) stored at chunk^(d&7).
__global__ __launch_bounds__(256) void k_prep(
    const float* __restrict__ w1, const float* __restrict__ w2,
    const float* __restrict__ rw1, const float* __restrict__ rw2,
    unsigned short* __restrict__ w1T, unsigned short* __restrict__ w2T,
    unsigned short* __restrict__ rw1T, unsigned short* __restrict__ rw2T) {
  int t = blockIdx.x * 256 + threadIdx.x;
  if (t < 128 * 128) {
    int c = t >> 7, d = t & 127;
    int pos = d * 128 + ((((c >> 3) ^ (d & 15)) << 3) | (c & 7));
    w1T[pos] = f2bf(w1[t]);
    w2T[pos] = f2bf(w2[t]);
  }
  if (t < 27 * 64 * 64) {
    int k = t >> 12, r = t & 4095, c = r >> 6, d = r & 63;
    int pos = (k << 12) + d * 64 + ((((c >> 3) ^ (d & 7)) << 3) | (c & 7));
    rw1T[pos] = f2bf(rw1[t]);
    rw2T[pos] = f2bf(rw2[t]);
  }
}

// ---- y = bf16(x) @ w1 + b1 ; w1T staged in LDS once ----
__global__ __launch_bounds__(256) void k_gemm_in(
    const float* __restrict__ x, const unsigned short* __restrict__ w1T,
    const float* __restrict__ b1, unsigned short* __restrict__ y) {
  __shared__ unsigned short sw[16384]; // 32KB
  const int tid = threadIdx.x, lane = tid & 63, w = tid >> 6;
  const int m16 = lane & 15, q = lane >> 4;
#pragma unroll
  for (int r = 0; r < 8; ++r) {
    const int off = (w * 8 + r) * 512 + lane * 8;
    gload_lds16(w1T + off, &sw[off]);
  }
  __syncthreads();
  const int rowbase = blockIdx.x * 128 + w * 32;
  f32x4 acc[2][8] = {};
#pragma unroll
  for (int kk = 0; kk < 4; ++kk) {
    frag_ab a[2];
#pragma unroll
    for (int rt = 0; rt < 2; ++rt) {
      int r0 = rowbase + rt * 16 + m16;
      int rc = r0 < N_PTS ? r0 : N_PTS - 1;
      const float* xp = x + (size_t)rc * 128 + kk * 32 + q * 8;
      float4 f0 = *(const float4*)xp;
      float4 f1 = *(const float4*)(xp + 4);
      frag_ab t;
      t[0] = (short)f2bf(f0.x); t[1] = (short)f2bf(f0.y);
      t[2] = (short)f2bf(f0.z); t[3] = (short)f2bf(f0.w);
      t[4] = (short)f2bf(f1.x); t[5] = (short)f2bf(f1.y);
      t[6] = (short)f2bf(f1.z); t[7] = (short)f2bf(f1.w);
      a[rt] = t;
    }
#pragma unroll
    for (int ct = 0; ct < 8; ++ct) {
      const int d = ct * 16 + m16;
      const int phys = ((kk << 2) | q) ^ m16;
      frag_ab bf = *(const frag_ab*)(&sw[d * 128 + phys * 8]);
      acc[0][ct] = __builtin_amdgcn_mfma_f32_16x16x32_bf16(a[0], bf, acc[0][ct], 0, 0, 0);
      acc[1][ct] = __builtin_amdgcn_mfma_f32_16x16x32_bf16(a[1], bf, acc[1][ct], 0, 0, 0);
    }
  }
#pragma unroll
  for (int ct = 0; ct < 8; ++ct) {
    const int col = ct * 16 + m16;
    const float bias = b1[col];
#pragma unroll
    for (int rt = 0; rt < 2; ++rt)
#pragma unroll
      for (int j = 0; j < 4; ++j) {
        int r = rowbase + rt * 16 + q * 4 + j;
        if (r < N_PTS) y[(size_t)r * 128 + col] = f2bf(acc[rt][ct][j] + bias);
      }
  }
}

// ---- gathered sparse conv, B via double-buffered LDS ----
template <bool FUSE>
__global__ __launch_bounds__(256) void k_conv(
    const unsigned short* __restrict__ feat, const int fstride,
    const int* __restrict__ nbr,
    const unsigned short* __restrict__ rwT, const float* __restrict__ rb,
    const unsigned short* __restrict__ res, unsigned short* __restrict__ out) {
  __shared__ unsigned short sw[2][4096]; // 2 x 8KB ping-pong
  const int tid = threadIdx.x, lane = tid & 63, w = tid >> 6;
  const int m16 = lane & 15, q = lane >> 4;
  const int rowbase = blockIdx.x * 128 + w * 32;
  const int p0 = rowbase + m16, p1 = p0 + 16;
  const bool v0 = p0 < N_PTS, v1 = p1 < N_PTS;
  const int s0 = w * 1024 + lane * 8; // ushort index of this thread's 16B chunk, round 0
  const int s1 = s0 + 512;            // round 1

  int i0r[2], i1r[2];
  i0r[0] = v0 ? nbr[p0] : -1;
  i1r[0] = v1 ? nbr[p1] : -1;
  i0r[1] = v0 ? nbr[N_PTS + p0] : -1;
  i1r[1] = v1 ? nbr[N_PTS + p1] : -1;

  frag_ab A[2][2][2]; // [ring][rt][kk]
#pragma unroll
  for (int a = 0; a < 2; ++a)
#pragma unroll
    for (int b = 0; b < 2; ++b)
#pragma unroll
      for (int c = 0; c < 2; ++c) A[a][b][c] = ZFRAG;

  { // stage k=0, gather A for k=0
    const unsigned short* src = rwT;
    gload_lds16(src + s0, &sw[0][s0]);
    gload_lds16(src + s1, &sw[0][s1]);
    if (i0r[0] >= 0) {
      const unsigned short* fp = feat + (size_t)i0r[0] * fstride + q * 8;
      A[0][0][0] = *(const frag_ab*)fp; A[0][0][1] = *(const frag_ab*)(fp + 32);
    }
    if (i1r[0] >= 0) {
      const unsigned short* fp = feat + (size_t)i1r[0] * fstride + q * 8;
      A[0][1][0] = *(const frag_ab*)fp; A[0][1][1] = *(const frag_ab*)(fp + 32);
    }
  }
  __syncthreads();

  f32x4 acc[2][4] = {};
#pragma unroll
  for (int k = 0; k < 27; ++k) {
    const int b = k & 1;
    if (k + 1 < 27) {
      // stage weights for k+1 into other buffer
      const unsigned short* src = rwT + ((k + 1) << 12);
      gload_lds16(src + s0, &sw[b ^ 1][s0]);
      gload_lds16(src + s1, &sw[b ^ 1][s1]);
      // gather A for k+1 (indices already resolved)
      const int n = (k + 1) & 1;
      int j0 = i0r[n], j1 = i1r[n];
      A[n][0][0] = ZFRAG; A[n][0][1] = ZFRAG; A[n][1][0] = ZFRAG; A[n][1][1] = ZFRAG;
      if (j0 >= 0) {
        const unsigned short* fp = feat + (size_t)j0 * fstride + q * 8;
        A[n][0][0] = *(const frag_ab*)fp; A[n][0][1] = *(const frag_ab*)(fp + 32);
      }
      if (j1 >= 0) {
        const unsigned short* fp = feat + (size_t)j1 * fstride + q * 8;
        A[n][1][0] = *(const frag_ab*)fp; A[n][1][1] = *(const frag_ab*)(fp + 32);
      }
    }
    if (k + 2 < 27) {
      i0r[k & 1] = v0 ? nbr[(k + 2) * N_PTS + p0] : -1;
      i1r[k & 1] = v1 ? nbr[(k + 2) * N_PTS + p1] : -1;
    }
    // compute k from sw[b], A[b]
#pragma unroll
    for (int kk = 0; kk < 2; ++kk)
#pragma unroll
      for (int ct = 0; ct < 4; ++ct) {
        const int d = ct * 16 + m16;
        const int phys = ((kk << 2) | q) ^ (m16 & 7);
        frag_ab bf = *(const frag_ab*)(&sw[b][d * 64 + phys * 8]);
        acc[0][ct] = __builtin_amdgcn_mfma_f32_16x16x32_bf16(A[b][0][kk], bf, acc[0][ct], 0, 0, 0);
        acc[1][ct] = __builtin_amdgcn_mfma_f32_16x16x32_bf16(A[b][1][kk], bf, acc[1][ct], 0, 0, 0);
      }
    __syncthreads();
  }

#pragma unroll
  for (int ct = 0; ct < 4; ++ct) {
    const int col = ct * 16 + m16;
    const float bias = rb[col];
#pragma unroll
    for (int rt = 0; rt < 2; ++rt)
#pragma unroll
      for (int j = 0; j < 4; ++j) {
        const int r = rowbase + rt * 16 + q * 4 + j;
        if (r < N_PTS) {
          float v = acc[rt][ct][j] + bias;
          v = v > 0.f ? v : 0.f;
          if constexpr (FUSE) v += 2.f * bf2f(res[(size_t)r * 128 + col]);
          out[(size_t)r * 64 + col] = f2bf(v);
        }
      }
  }
}

// ---- out = x + [z1 | y[:,64:]] @ w2 + b2 ; w2T staged in LDS once ----
__global__ __launch_bounds__(256) void k_gemm_out(
    const float* __restrict__ x, const unsigned short* __restrict__ z1,
    const unsigned short* __restrict__ y, const unsigned short* __restrict__ w2T,
    const float* __restrict__ b2, float* __restrict__ out) {
  __shared__ unsigned short sw[16384]; // 32KB
  const int tid = threadIdx.x, lane = tid & 63, w = tid >> 6;
  const int m16 = lane & 15, q = lane >> 4;
#pragma unroll
  for (int r = 0; r < 8; ++r) {
    const int off = (w * 8 + r) * 512 + lane * 8;
    gload_lds16(w2T + off, &sw[off]);
  }
  __syncthreads();
  const int rowbase = blockIdx.x * 128 + w * 32;
  f32x4 acc[2][8] = {};
#pragma unroll
  for (int kk = 0; kk < 4; ++kk) {
    frag_ab a[2];
#pragma unroll
    for (int rt = 0; rt < 2; ++rt) {
      int r0 = rowbase + rt * 16 + m16;
      int rc = r0 < N_PTS ? r0 : N_PTS - 1;
      const unsigned short* ap = (kk < 2)
          ? (z1 + (size_t)rc * 64 + kk * 32 + q * 8)
          : (y + (size_t)rc * 128 + 64 + (kk - 2) * 32 + q * 8);
      a[rt] = *(const frag_ab*)ap;
    }
#pragma unroll
    for (int ct = 0; ct < 8; ++ct) {
      const int d = ct * 16 + m16;
      const int phys = ((kk << 2) | q) ^ m16;
      frag_ab bf = *(const frag_ab*)(&sw[d * 128 + phys * 8]);
      acc[0][ct] = __builtin_amdgcn_mfma_f32_16x16x32_bf16(a[0], bf, acc[0][ct], 0, 0, 0);
      acc[1][ct] = __builtin_amdgcn_mfma_f32_16x16x32_bf16(a[1], bf, acc[1][ct], 0, 0, 0);
    }
  }
#pragma unroll
  for (int ct = 0; ct < 8; ++ct) {
    const int col = ct * 16 + m16;
    const float bias = b2[col];
#pragma unroll
    for (int rt = 0; rt < 2; ++rt)
#pragma unroll
      for (int j = 0; j < 4; ++j) {
        int r = rowbase + rt * 16 + q * 4 + j;
        if (r < N_PTS) {
          size_t o = (size_t)r * 128 + col;
          out[o] = acc[rt][ct][j] + bias + x[o];
        }
      }
  }
}

extern "C" void kernel_launch(void* const* d_in, const int* in_sizes, int n_in,
                              void* d_out, int out_size, void* d_ws, size_t ws_size,
                              hipStream_t stream) {
  const float* x   = (const float*)d_in[0];
  const float* w1  = (const float*)d_in[1];
  const float* b1  = (const float*)d_in[2];
  const float* w2  = (const float*)d_in[3];
  const float* b2  = (const float*)d_in[4];
  const float* rw1 = (const float*)d_in[5];
  const float* rb1 = (const float*)d_in[6];
  const float* rw2 = (const float*)d_in[7];
  const float* rb2 = (const float*)d_in[8];
  const int* nbr = (const int*)d_in[9];
  float* out = (float*)d_out;

  char* ws = (char*)d_ws;
  unsigned short* w1T  = (unsigned short*)(ws);                       // 32 KB
  unsigned short* w2T  = (unsigned short*)(ws + 32768);               // 32 KB
  unsigned short* rw1T = (unsigned short*)(ws + 65536);               // 216 KB
  unsigned short* rw2T = (unsigned short*)(ws + 286720);              // 216 KB
  unsigned short* y    = (unsigned short*)(ws + 507904);              // 25.6 MB
  unsigned short* r1   = (unsigned short*)(ws + 507904 + 25600000);   // 12.8 MB
  unsigned short* z1   = (unsigned short*)(ws + 507904 + 38400000);   // 12.8 MB

  k_prep<<<432, 256, 0, stream>>>(w1, w2, rw1, rw2, w1T, w2T, rw1T, rw2T);
  k_gemm_in<<<NBLK128, 256, 0, stream>>>(x, w1T, b1, y);
  k_conv<false><<<NBLK128, 256, 0, stream>>>(y, 128, nbr, rw1T, rb1, nullptr, r1);
  k_conv<true><<<NBLK128, 256, 0, stream>>>(r1, 64, nbr, rw2T, rb2, y, z1);
  k_gemm_out<<<NBLK128, 256, 0, stream>>>(x, z1, y, w2T, b2, out);
}